// Round 5
// baseline (136.405 us; speedup 1.0000x reference)
//
#include <hip/hip_runtime.h>

// IndexedLinear: out[z, s*V:(s+1)*V] = coeff[s] * x[z, s*U:(s+1)*U] @ W[seg(z), s]
// S=8, U=V=32, C=32, Z=65536.
//
// R10 — DIAGNOSTIC ROUND (intentional ~35us regression, revert next round).
// R5/R6/R8/R9 (four disjoint structures) all land 118-123us; kernel-only
// ~33-38us vs 20.5us roofline, and the kernel has NEVER appeared in the
// rocprof top-5 (all ~42us harness fills; ~85us of dur_us is fixed reset).
// This round runs the R8 body TWICE in one dispatch (~70us -> top-1 in
// rocprof) to finally read OUR counters:
//   FETCH_SIZE >= ~180 MiB  => W/L2 thrash (H1) -> W-stationary redesign
//   FETCH_SIZE ~= 120-140   => BW under-utilization (H2) -> issue/MLP work
//   hbm_gbps   ~= 6000+     => already at achievable BW -> roofline case
// Pass 2 recomputes and rewrites identical values (idempotent => correct).
// Pointers are laundered through an opaque SGPR offset each pass so the
// compiler can neither CSE pass-2 loads nor dead-store-eliminate pass-1
// stores (rule #17: ablation-via-skip DCEs upstream ops).

constexpr int S = 8, U = 32, V = 32, C = 32, Z = 65536;
constexpr int SU = S * U;   // 256 floats per X row
constexpr int SV = S * V;   // 256 floats per out row
constexpr int NT = 256;     // 4 waves
constexpr int BZ = 32;      // z rows per block; wave w handles s in {2w, 2w+1}

typedef float    f4     __attribute__((ext_vector_type(4)));
typedef float    f32x16 __attribute__((ext_vector_type(16)));
typedef short    bf16x8 __attribute__((ext_vector_type(8)));
typedef unsigned u32x4  __attribute__((ext_vector_type(4)));

// packed RNE f32x2 -> bf16x2 (low = lo, high = hi)
__device__ __forceinline__ unsigned cvtpk(float lo, float hi) {
  unsigned r;
  asm("v_cvt_pk_bf16_f32 %0, %1, %2" : "=v"(r) : "v"(lo), "v"(hi));
  return r;
}

__global__ __launch_bounds__(NT) void IndexedLinear_kernel(
    const float* __restrict__ W_all,   // (C, S*U*V)
    const float* __restrict__ X,       // (Z, S*U)
    const int*   __restrict__ counts,  // (C,)
    const float* __restrict__ coeff,   // (S,)
    float*       __restrict__ out)     // (Z, S*V)
{
  const int tid  = threadIdx.x;
  const int lane = tid & 63;
  const int w    = tid >> 6;
  const int z0   = blockIdx.x * BZ;

  const int m  = lane & 31;   // A row / B col / C col
  const int h  = lane >> 5;   // k-half
  const int s0 = 2 * w;

  // ---- segment exclusive-prefix scan (per wave) ----
  int cnt = (lane < C) ? counts[lane] : 0;
  int inc = cnt;
  #pragma unroll
  for (int d = 1; d < 32; d <<= 1) {
    int o = __shfl_up(inc, d, 64);
    if (lane >= d) inc += o;
  }
  const int exc = inc - cnt;
  const unsigned long long ma = __ballot(lane < C && exc <= z0);
  const unsigned long long mb = __ballot(lane < C && exc <= z0 + BZ - 1);
  const int segA = __popcll(ma) - 1;
  const int segB = __popcll(mb) - 1;
  const bool uni = (segA == segB);

  #pragma unroll 1
  for (int rep = 0; rep < 2; ++rep) {
    // launder bases through an opaque zero offset: defeats cross-pass load
    // CSE and pass-1 dead-store elimination without changing addresses.
    long off = 0;
    asm volatile("" : "+s"(off));
    const float* Xp = X + off;
    const float* Wp = W_all + off;
    float*       op = out + off;

    if (uni) {
      // ---- A: lane (m,h) loads contiguous 32B row slices (8x dwordx4) ----
      const f4* Xr = (const f4*)Xp + (size_t)(z0 + m) * (SU / 4) + 2 * h;
      f4 xs[8];
      #pragma unroll
      for (int tt = 0; tt < 2; ++tt) {
        const int c0 = (s0 + tt) * 8;
        xs[4 * tt + 0] = Xr[c0 + 0];
        xs[4 * tt + 1] = Xr[c0 + 1];
        xs[4 * tt + 2] = Xr[c0 + 4];
        xs[4 * tt + 3] = Xr[c0 + 5];
      }

      // ---- B fragments (W slice, coeff folded), packed converts ----
      const float* wseg = Wp + (size_t)segA * (S * U * V);
      u32x4 b1[2], b2[2];
      #pragma unroll
      for (int tt = 0; tt < 2; ++tt) {
        const int s = s0 + tt;
        const float cs = coeff[s];
        const float* wb = wseg + s * (U * V) + m;
        #pragma unroll
        for (int j = 0; j < 4; ++j) {
          b1[tt][j] = cvtpk(wb[(8 * h + 2 * j) * V] * cs,
                            wb[(8 * h + 2 * j + 1) * V] * cs);
          b2[tt][j] = cvtpk(wb[(16 + 8 * h + 2 * j) * V] * cs,
                            wb[(16 + 8 * h + 2 * j + 1) * V] * cs);
        }
      }

      #pragma unroll
      for (int tt = 0; tt < 2; ++tt) {
        const int s = s0 + tt;
        const f4 xa = xs[4 * tt + 0], xb = xs[4 * tt + 1];
        const f4 xc = xs[4 * tt + 2], xd = xs[4 * tt + 3];
        u32x4 pa, pb;
        pa[0] = cvtpk(xa[0], xa[1]); pa[1] = cvtpk(xa[2], xa[3]);
        pa[2] = cvtpk(xb[0], xb[1]); pa[3] = cvtpk(xb[2], xb[3]);
        pb[0] = cvtpk(xc[0], xc[1]); pb[1] = cvtpk(xc[2], xc[3]);
        pb[2] = cvtpk(xd[0], xd[1]); pb[3] = cvtpk(xd[2], xd[3]);
        const bf16x8 a1 = __builtin_bit_cast(bf16x8, pa);
        const bf16x8 a2 = __builtin_bit_cast(bf16x8, pb);
        f32x16 acc = {};
        acc = __builtin_amdgcn_mfma_f32_32x32x16_bf16(
            a1, __builtin_bit_cast(bf16x8, b1[tt]), acc, 0, 0, 0);
        acc = __builtin_amdgcn_mfma_f32_32x32x16_bf16(
            a2, __builtin_bit_cast(bf16x8, b2[tt]), acc, 0, 0, 0);

        // verified C/D map: reg r -> row (r&3)+8*(r>>2)+4h, col m.
        float* ob = op + (size_t)z0 * SV + s * V + m;
        #pragma unroll
        for (int r = 0; r < 16; ++r) {
          const int row = (r & 3) + 8 * (r >> 2) + 4 * h;
          __builtin_nontemporal_store(acc[r], ob + (size_t)row * SV);
        }
      }
    } else {
      // ---- fallback: block crosses a segment boundary (fp32 exact) ----
      const int zz = z0 + m;
      int sg = 0;
      #pragma unroll 1
      for (int i = 1; i < C; ++i) {
        const int pi = __shfl(exc, i, 64);
        if (pi <= zz) sg = i;
      }
      #pragma unroll 1
      for (int tt = 0; tt < 2; ++tt) {
        const int s = s0 + tt;
        const float cs = coeff[s];
        const float* wr = Wp + (size_t)sg * (S * U * V) + s * (U * V) + 16 * h;
        float accv[16] = {};
        #pragma unroll 1
        for (int cq = 0; cq < 8; ++cq) {
          const f4 xv = ((const f4*)Xp)[(size_t)zz * (SU / 4) + s * 8 + cq];
          #pragma unroll
          for (int ii = 0; ii < 4; ++ii) {
            const int u = cq * 4 + ii;
            const float xu = xv[ii];
            #pragma unroll
            for (int j = 0; j < 16; ++j) accv[j] += xu * wr[u * V + j];
          }
        }
        float* ob = op + (size_t)zz * SV + s * V + 16 * h;
        #pragma unroll
        for (int j = 0; j < 16; ++j) ob[j] = accv[j] * cs;
      }
    }
    asm volatile("" ::: "memory");
  }
}

extern "C" void kernel_launch(void* const* d_in, const int* in_sizes, int n_in,
                              void* d_out, int out_size, void* d_ws, size_t ws_size,
                              hipStream_t stream) {
  const float* input1       = (const float*)d_in[0];  // (C, S*U*V)
  const float* input2       = (const float*)d_in[1];  // (Z, S*U)
  const int*   counts       = (const int*)d_in[2];    // (C,)
  const float* coefficients = (const float*)d_in[3];  // (S,)
  float*       out          = (float*)d_out;          // (Z, S*V)

  const int grid = Z / BZ;  // 2048 blocks, 4 independent waves each, no LDS
  IndexedLinear_kernel<<<grid, NT, 0, stream>>>(input1, input2, counts,
                                                coefficients, out);
}

// Round 6
// 119.076 us; speedup vs baseline: 1.1455x; 1.1455x over previous
//
#include <hip/hip_runtime.h>

// IndexedLinear: out[z, s*V:(s+1)*V] = coeff[s] * x[z, s*U:(s+1)*U] @ W[seg(z), s]
// S=8, U=V=32, C=32, Z=65536.
//
// R11: persistent pipelined streaming (no LDS, no barriers).
// R10 diagnostic (2-pass, kernel top-1 in rocprof) measured per pass:
//   FETCH ~18 MiB (X is L3-resident!), WRITE ~66 MiB, 3.0 TB/s,
//   MfmaUtil 1.3%, VALUBusy 7.8%, Occupancy 19%  => latency/overhead-bound,
//   NOT bandwidth-bound (roofline for this traffic ~14us; we take ~28).
// Cause: 2048 single-tile blocks, each pays a full serial load->convert->
// MFMA->store->drain chain (~3.5us) with nothing overlapped.
// Fix (untested combo): register prefetch pipeline ACROSS tiles + zero
// barriers + persistent waves:
//   - grid 512, TPB=4 tiles/wave; issue tile t+1's 8 X dwordx4 loads before
//     computing tile t. vmcnt retires in-order => compiler's counted waits
//     overlap tile-t stores with tile-t+1 loads; no inline waitcnt needed.
//   - B fragments (W slice, coeff folded, packed cvt) cached across tiles,
//     rebuilt only on segment change (counts=2048 -> once per block).
//   - one store drain per 4 tiles (wave end) instead of per tile.
//   - verified maps carried: A/B frag layout, C/D store map (2 full 128B
//     lines per store instr), fp32-exact fallback for boundary tiles.

constexpr int S = 8, U = 32, V = 32, C = 32, Z = 65536;
constexpr int SU = S * U;   // 256 floats per X row
constexpr int SV = S * V;   // 256 floats per out row
constexpr int NT = 256;     // 4 waves; wave w owns s in {2w, 2w+1}
constexpr int BZ = 32;      // z rows per tile
constexpr int TPB = 4;      // tiles per block -> grid 512

typedef float    f4     __attribute__((ext_vector_type(4)));
typedef float    f32x16 __attribute__((ext_vector_type(16)));
typedef short    bf16x8 __attribute__((ext_vector_type(8)));
typedef unsigned u32x4  __attribute__((ext_vector_type(4)));

// packed RNE f32x2 -> bf16x2 (bit-identical to verified manual f2bf)
__device__ __forceinline__ unsigned cvtpk(float lo, float hi) {
  unsigned r;
  asm("v_cvt_pk_bf16_f32 %0, %1, %2" : "=v"(r) : "v"(lo), "v"(hi));
  return r;
}

__device__ __forceinline__ short f2bf(float f) {
  unsigned u = __builtin_bit_cast(unsigned, f);
  u = (u + 0x7FFFu + ((u >> 16) & 1u)) >> 16;
  return (short)u;
}

// issue the 8 X row-slice loads for one tile into dst[0..7]
#define LOADX(dst, zt)                                                        \
  do {                                                                        \
    const f4* Xr_ = (const f4*)X + (size_t)((zt) + m) * (SU / 4) + 2 * h;     \
    dst[0] = Xr_[c0 + 0];  dst[1] = Xr_[c0 + 1];                              \
    dst[2] = Xr_[c0 + 4];  dst[3] = Xr_[c0 + 5];                              \
    dst[4] = Xr_[c0 + 8];  dst[5] = Xr_[c0 + 9];                              \
    dst[6] = Xr_[c0 + 12]; dst[7] = Xr_[c0 + 13];                             \
  } while (0)

__global__ __launch_bounds__(NT) void IndexedLinear_kernel(
    const float* __restrict__ W_all,   // (C, S*U*V)
    const float* __restrict__ X,       // (Z, S*U)
    const int*   __restrict__ counts,  // (C,)
    const float* __restrict__ coeff,   // (S,)
    float*       __restrict__ out)     // (Z, S*V)
{
  const int tid  = threadIdx.x;
  const int lane = tid & 63;
  const int w    = tid >> 6;
  const int zb   = blockIdx.x * (BZ * TPB);

  const int m  = lane & 31;   // A row / B col / C col
  const int h  = lane >> 5;   // k-half
  const int s0 = 2 * w;
  const int c0 = s0 * 8;      // f4-chunk base of this wave's s-pair

  // ---- prefetch tile 0 immediately (latency starts before anything else) --
  f4 xA[8], xB[8];
  LOADX(xA, zb);

  // ---- segment exclusive-prefix scan (overlaps tile-0 loads) ----
  int cnt = (lane < C) ? counts[lane] : 0;
  int inc = cnt;
  #pragma unroll
  for (int d = 1; d < 32; d <<= 1) {
    int o = __shfl_up(inc, d, 64);
    if (lane >= d) inc += o;
  }
  const int exc = inc - cnt;

  int curseg = -1;
  u32x4 b1[2], b2[2];

  #pragma unroll
  for (int t = 0; t < TPB; ++t) {
    f4* cur = (t & 1) ? xB : xA;   // static after full unroll
    f4* nxt = (t & 1) ? xA : xB;
    const int z0 = zb + t * BZ;

    // ---- issue next tile's loads BEFORE consuming current tile ----
    if (t + 1 < TPB) LOADX(nxt, z0 + BZ);

    // per-tile segment ids (register-only, cheap)
    const unsigned long long ma = __ballot(lane < C && exc <= z0);
    const unsigned long long mb = __ballot(lane < C && exc <= z0 + BZ - 1);
    const int segA = __popcll(ma) - 1;
    const int segB = __popcll(mb) - 1;
    const bool uni = (segA == segB);

    if (uni) {
      if (segA != curseg) {
        // ---- (re)build B fragments: W slice, coeff folded, packed cvt ----
        curseg = segA;
        const float* wseg = W_all + (size_t)segA * (S * U * V);
        #pragma unroll
        for (int tt = 0; tt < 2; ++tt) {
          const int s = s0 + tt;
          const float cs = coeff[s];
          const float* wb = wseg + s * (U * V) + m;
          #pragma unroll
          for (int j = 0; j < 4; ++j) {
            b1[tt][j] = cvtpk(wb[(8 * h + 2 * j) * V] * cs,
                              wb[(8 * h + 2 * j + 1) * V] * cs);
            b2[tt][j] = cvtpk(wb[(16 + 8 * h + 2 * j) * V] * cs,
                              wb[(16 + 8 * h + 2 * j + 1) * V] * cs);
          }
        }
      }

      #pragma unroll
      for (int tt = 0; tt < 2; ++tt) {
        const int s = s0 + tt;
        const f4 xa = cur[4 * tt + 0], xb = cur[4 * tt + 1];
        const f4 xc = cur[4 * tt + 2], xd = cur[4 * tt + 3];
        u32x4 pa, pb;
        pa[0] = cvtpk(xa[0], xa[1]); pa[1] = cvtpk(xa[2], xa[3]);
        pa[2] = cvtpk(xb[0], xb[1]); pa[3] = cvtpk(xb[2], xb[3]);
        pb[0] = cvtpk(xc[0], xc[1]); pb[1] = cvtpk(xc[2], xc[3]);
        pb[2] = cvtpk(xd[0], xd[1]); pb[3] = cvtpk(xd[2], xd[3]);
        const bf16x8 a1 = __builtin_bit_cast(bf16x8, pa);
        const bf16x8 a2 = __builtin_bit_cast(bf16x8, pb);
        f32x16 acc = {};
        acc = __builtin_amdgcn_mfma_f32_32x32x16_bf16(
            a1, __builtin_bit_cast(bf16x8, b1[tt]), acc, 0, 0, 0);
        acc = __builtin_amdgcn_mfma_f32_32x32x16_bf16(
            a2, __builtin_bit_cast(bf16x8, b2[tt]), acc, 0, 0, 0);

        // verified C/D map: reg r -> row (r&3)+8*(r>>2)+4h, col m.
        // each store instr = 2 full 128B lines (rows R and R+4).
        float* ob = out + (size_t)z0 * SV + s * V + m;
        #pragma unroll
        for (int r = 0; r < 16; ++r) {
          const int row = (r & 3) + 8 * (r >> 2) + 4 * h;
          __builtin_nontemporal_store(acc[r], ob + (size_t)row * SV);
        }
      }
    } else {
      // ---- fallback: tile crosses a segment boundary (fp32 exact) ----
      const int zz = z0 + m;
      int sg = 0;
      #pragma unroll 1
      for (int i = 1; i < C; ++i) {
        const int pi = __shfl(exc, i, 64);
        if (pi <= zz) sg = i;
      }
      #pragma unroll 1
      for (int tt = 0; tt < 2; ++tt) {
        const int s = s0 + tt;
        const float cs = coeff[s];
        const float* wr = W_all + (size_t)sg * (S * U * V) + s * (U * V) + 16 * h;
        float accv[16] = {};
        #pragma unroll 1
        for (int cq = 0; cq < 8; ++cq) {
          const f4 xv = ((const f4*)X)[(size_t)zz * (SU / 4) + s * 8 + cq];
          #pragma unroll
          for (int ii = 0; ii < 4; ++ii) {
            const int u = cq * 4 + ii;
            const float xu = xv[ii];
            #pragma unroll
            for (int j = 0; j < 16; ++j) accv[j] += xu * wr[u * V + j];
          }
        }
        float* ob = out + (size_t)zz * SV + s * V + 16 * h;
        #pragma unroll
        for (int j = 0; j < 16; ++j) ob[j] = accv[j] * cs;
      }
    }
  }
}

extern "C" void kernel_launch(void* const* d_in, const int* in_sizes, int n_in,
                              void* d_out, int out_size, void* d_ws, size_t ws_size,
                              hipStream_t stream) {
  const float* input1       = (const float*)d_in[0];  // (C, S*U*V)
  const float* input2       = (const float*)d_in[1];  // (Z, S*U)
  const int*   counts       = (const int*)d_in[2];    // (C,)
  const float* coefficients = (const float*)d_in[3];  // (S,)
  float*       out          = (float*)d_out;          // (Z, S*V)

  const int grid = Z / (BZ * TPB);  // 512 blocks, 4 indep waves, no LDS
  IndexedLinear_kernel<<<grid, NT, 0, stream>>>(input1, input2, counts,
                                                coefficients, out);
}

// Round 7
// 118.300 us; speedup vs baseline: 1.1530x; 1.0066x over previous
//
#include <hip/hip_runtime.h>

// IndexedLinear: out[z, s*V:(s+1)*V] = coeff[s] * x[z, s*U:(s+1)*U] @ W[seg(z), s]
// S=8, U=V=32, C=32, Z=65536.
//
// R12: wave-private LDS staging + ZERO barriers + store-aware counted vmcnt.
// Evidence: R5/R6 (coalesced DMA staging, but block barriers + vmcnt that
// also waited on outstanding stores) == R8/R9/R11 (barrier-free, but A-load
// instrs scatter 32B-used per 128B line across 32 lines) == 118-123us.
// R10 counters: all pipes idle (MfmaUtil 1.3%, VALU 8%, Occ 19%, 3.0 TB/s)
// => latency/transaction-bound. R12 is the first kernel with BOTH clean
// per-instruction coalescing AND no cross-wave serialization:
//  - wave w stages its own 32-row x 256B slice (chunks 16w..16w+15) via
//    8x global_load_lds: instr k reads rows 4k..4k+3 fully contiguous
//    (4 x 256B = 8 FULL lines). Per-lane global addr bakes the XOR swizzle
//    slot(row,cc) = cc ^ (row&7) into linear LDS (rule #21: swizzle source
//    + read, never the gload_lds dest), so ds_read_b128 by lane (m,h) hits
//    all 8 bank-groups (conflict-free beyond the free 2-way).
//  - NO __syncthreads anywhere; wave waits only on ITS own DMA:
//    t=0: vmcnt(8) (8 next-tile loads in flight); 0<t<3: vmcnt(40)
//    (skips 32 older nt stores + 8 newer loads; vmcnt is in-order so
//    <=40 outstanding <=> this tile's 8 loads retired); t=3: vmcnt(32).
//    Loads NEVER wait on stores (R6's hidden flaw).
//  - TPB=4 persistent, double-buffered private LDS (4w x 2 x 8KiB = 64KiB,
//    2 blocks/CU), B-frags cached per segment, nt stores, verified A/B/C/D
//    maps and fp32-exact boundary fallback carried from R5..R11.

constexpr int S = 8, U = 32, V = 32, C = 32, Z = 65536;
constexpr int SU = S * U;   // 256 floats per X row
constexpr int SV = S * V;   // 256 floats per out row
constexpr int NT = 256;     // 4 waves; wave w owns s in {2w, 2w+1}
constexpr int BZ = 32;      // z rows per tile
constexpr int TPB = 4;      // tiles per block -> grid 512

typedef float    f4     __attribute__((ext_vector_type(4)));
typedef float    f32x16 __attribute__((ext_vector_type(16)));
typedef short    bf16x8 __attribute__((ext_vector_type(8)));
typedef unsigned u32x4  __attribute__((ext_vector_type(4)));

typedef const __attribute__((address_space(1))) unsigned gu32;
typedef __attribute__((address_space(3))) unsigned lu32;

// packed RNE f32x2 -> bf16x2 (bit-identical to verified manual f2bf)
__device__ __forceinline__ unsigned cvtpk(float lo, float hi) {
  unsigned r;
  asm("v_cvt_pk_bf16_f32 %0, %1, %2" : "=v"(r) : "v"(lo), "v"(hi));
  return r;
}

__global__ __launch_bounds__(NT) void IndexedLinear_kernel(
    const float* __restrict__ W_all,   // (C, S*U*V)
    const float* __restrict__ X,       // (Z, S*U)
    const int*   __restrict__ counts,  // (C,)
    const float* __restrict__ coeff,   // (S,)
    float*       __restrict__ out)     // (Z, S*V)
{
  const int tid  = threadIdx.x;
  const int lane = tid & 63;
  const int w    = tid >> 6;
  const int zb   = blockIdx.x * (BZ * TPB);

  const int m  = lane & 31;   // A row / B col / C col
  const int h  = lane >> 5;   // k-half
  const int s0 = 2 * w;
  const int c0 = 16 * w;      // wave's f4-chunk base within an X row
  const int mx = m & 7;       // XOR key for swizzled LDS reads

  // wave-private LDS: [wave][buf][32 rows][16 f4-slots]; slot sc of row r
  // holds global chunk c0 + (sc ^ (r&7)).
  __shared__ f4 XL[4 * 2 * 512];  // 64 KiB
  const int wbase = w * 1024;

  // staging lane decomposition: instr k covers rows 4k..4k+3
  const int rg = lane >> 4;   // row-group within instr (0..3)
  const int ci = lane & 15;   // slot index within row (0..15)

  // ---- stage tile 0 -> buf 0 (kick DMA before anything else) ----
  #pragma unroll
  for (int k = 0; k < 8; ++k) {
    const int r  = 4 * k + rg;                 // row within tile (z = zt + r)
    const int cc = ci ^ (r & 7);               // global chunk for this slot
    const char* gp = (const char*)X
        + ((size_t)(zb + r) * SU + (c0 + cc) * 4) * 4;
    __builtin_amdgcn_global_load_lds((gu32*)gp, (lu32*)&XL[wbase + k * 64],
                                     16, 0, 0);
  }

  // ---- segment exclusive-prefix scan (overlaps tile-0 DMA) ----
  int cnt = (lane < C) ? counts[lane] : 0;
  int inc = cnt;
  #pragma unroll
  for (int d = 1; d < 32; d <<= 1) {
    int o = __shfl_up(inc, d, 64);
    if (lane >= d) inc += o;
  }
  const int exc = inc - cnt;

  int curseg = -1;
  u32x4 b1[2], b2[2];

  #pragma unroll
  for (int t = 0; t < TPB; ++t) {
    const int z0 = zb + t * BZ;
    const int bs = wbase + (t & 1) * 512;      // this tile's LDS base (f4)

    // ---- issue next tile's DMA into the other private buffer ----
    if (t + 1 < TPB) {
      const int nb = wbase + ((t + 1) & 1) * 512;
      #pragma unroll
      for (int k = 0; k < 8; ++k) {
        const int r  = 4 * k + rg;
        const int cc = ci ^ (r & 7);
        const char* gp = (const char*)X
            + ((size_t)(z0 + BZ + r) * SU + (c0 + cc) * 4) * 4;
        __builtin_amdgcn_global_load_lds((gu32*)gp, (lu32*)&XL[nb + k * 64],
                                         16, 0, 0);
      }
    }

    // ---- wait for THIS tile's 8 loads only (in-order vmcnt; skip newer
    //      loads and never wait on the older nt stores) ----
    if (t == 0)            asm volatile("s_waitcnt vmcnt(8)" ::: "memory");
    else if (t < TPB - 1)  asm volatile("s_waitcnt vmcnt(40)" ::: "memory");
    else                   asm volatile("s_waitcnt vmcnt(32)" ::: "memory");

    // per-tile segment ids
    const unsigned long long ma = __ballot(lane < C && exc <= z0);
    const unsigned long long mb = __ballot(lane < C && exc <= z0 + BZ - 1);
    const int segA = __popcll(ma) - 1;
    const int segB = __popcll(mb) - 1;
    const bool uni = (segA == segB);

    if (uni) {
      if (segA != curseg) {
        // ---- (re)build B fragments: W slice, coeff folded, packed cvt ----
        curseg = segA;
        const float* wseg = W_all + (size_t)segA * (S * U * V);
        #pragma unroll
        for (int tt = 0; tt < 2; ++tt) {
          const int s = s0 + tt;
          const float cs = coeff[s];
          const float* wb = wseg + s * (U * V) + m;
          #pragma unroll
          for (int j = 0; j < 4; ++j) {
            b1[tt][j] = cvtpk(wb[(8 * h + 2 * j) * V] * cs,
                              wb[(8 * h + 2 * j + 1) * V] * cs);
            b2[tt][j] = cvtpk(wb[(16 + 8 * h + 2 * j) * V] * cs,
                              wb[(16 + 8 * h + 2 * j + 1) * V] * cs);
          }
        }
      }

      #pragma unroll
      for (int tt = 0; tt < 2; ++tt) {
        const int s = s0 + tt;
        // A frags: swizzled ds_read_b128; lane (m,h) wants chunks
        // cc = tt*8 + 2h + {0,1,4,5} -> slot m*16 + (cc ^ (m&7)).
        const int cb = tt * 8 + 2 * h;
        const f4 xa = XL[bs + 16 * m + ((cb + 0) ^ mx)];
        const f4 xb = XL[bs + 16 * m + ((cb + 1) ^ mx)];
        const f4 xc = XL[bs + 16 * m + ((cb + 4) ^ mx)];
        const f4 xd = XL[bs + 16 * m + ((cb + 5) ^ mx)];
        u32x4 pa, pb;
        pa[0] = cvtpk(xa[0], xa[1]); pa[1] = cvtpk(xa[2], xa[3]);
        pa[2] = cvtpk(xb[0], xb[1]); pa[3] = cvtpk(xb[2], xb[3]);
        pb[0] = cvtpk(xc[0], xc[1]); pb[1] = cvtpk(xc[2], xc[3]);
        pb[2] = cvtpk(xd[0], xd[1]); pb[3] = cvtpk(xd[2], xd[3]);
        const bf16x8 a1 = __builtin_bit_cast(bf16x8, pa);
        const bf16x8 a2 = __builtin_bit_cast(bf16x8, pb);
        f32x16 acc = {};
        acc = __builtin_amdgcn_mfma_f32_32x32x16_bf16(
            a1, __builtin_bit_cast(bf16x8, b1[tt]), acc, 0, 0, 0);
        acc = __builtin_amdgcn_mfma_f32_32x32x16_bf16(
            a2, __builtin_bit_cast(bf16x8, b2[tt]), acc, 0, 0, 0);

        // verified C/D map: reg r -> row (r&3)+8*(r>>2)+4h, col m.
        // each store instr = 2 full 128B lines.
        float* ob = out + (size_t)z0 * SV + s * V + m;
        #pragma unroll
        for (int r = 0; r < 16; ++r) {
          const int row = (r & 3) + 8 * (r >> 2) + 4 * h;
          __builtin_nontemporal_store(acc[r], ob + (size_t)row * SV);
        }
      }
    } else {
      // ---- fallback: tile crosses a segment boundary (fp32 exact).
      //      Reads X directly from global; compiler-inserted waits for these
      //      loads drain older vmcnt entries, keeping the pipeline safe. ----
      const int zz = z0 + m;
      int sg = 0;
      #pragma unroll 1
      for (int i = 1; i < C; ++i) {
        const int pi = __shfl(exc, i, 64);
        if (pi <= zz) sg = i;
      }
      #pragma unroll 1
      for (int tt = 0; tt < 2; ++tt) {
        const int s = s0 + tt;
        const float cs = coeff[s];
        const float* wr = W_all + (size_t)sg * (S * U * V) + s * (U * V) + 16 * h;
        float accv[16] = {};
        #pragma unroll 1
        for (int cq = 0; cq < 8; ++cq) {
          const f4 xv = ((const f4*)X)[(size_t)zz * (SU / 4) + s * 8 + cq];
          #pragma unroll
          for (int ii = 0; ii < 4; ++ii) {
            const int u = cq * 4 + ii;
            const float xu = xv[ii];
            #pragma unroll
            for (int j = 0; j < 16; ++j) accv[j] += xu * wr[u * V + j];
          }
        }
        float* ob = out + (size_t)zz * SV + s * V + 16 * h;
        #pragma unroll
        for (int j = 0; j < 16; ++j) ob[j] = accv[j] * cs;
      }
    }
  }
}

extern "C" void kernel_launch(void* const* d_in, const int* in_sizes, int n_in,
                              void* d_out, int out_size, void* d_ws, size_t ws_size,
                              hipStream_t stream) {
  const float* input1       = (const float*)d_in[0];  // (C, S*U*V)
  const float* input2       = (const float*)d_in[1];  // (Z, S*U)
  const int*   counts       = (const int*)d_in[2];    // (C,)
  const float* coefficients = (const float*)d_in[3];  // (S,)
  float*       out          = (float*)d_out;          // (Z, S*V)

  const int grid = Z / (BZ * TPB);  // 512 blocks, 4 private waves, no barriers
  IndexedLinear_kernel<<<grid, NT, 0, stream>>>(input1, input2, counts,
                                                coefficients, out);
}